// Round 3
// baseline (1172.601 us; speedup 1.0000x reference)
//
#include <hip/hip_runtime.h>
#include <hip/hip_bf16.h>

#define DIM 128
#define CHUNK 4096
#define CAP 4096        // slab capacity per 128-node bucket (65 sigma above mean)
typedef __hip_bfloat16 bf16;
typedef __attribute__((ext_vector_type(8))) short bf16x8;   // 8 bf16 = 4 VGPRs
typedef __attribute__((ext_vector_type(4))) float f32x4;

// ============================ K1: prep ======================================
// b0: init slab cursors; b1: int-width detect (flagI: 0 -> int64); b2..17: W swizzle
__global__ void prep_kernel(int* __restrict__ bcursor, int nbuck,
                            const int* __restrict__ ei, int E, int* __restrict__ misc,
                            const float* __restrict__ W1, const float* __restrict__ W2,
                            bf16* __restrict__ Wsw1, bf16* __restrict__ Wsw2) {
    if (blockIdx.x == 0) {
        for (int i = threadIdx.x; i < nbuck; i += 256) bcursor[i] = i * CAP;
    } else if (blockIdx.x == 1) {
        __shared__ int s_or;
        if (threadIdx.x == 0) s_or = 0;
        __syncthreads();
        int lim = E < 16384 ? E : 16384;
        int acc = 0;
        for (int j = threadIdx.x; j < lim; j += 256) acc |= ei[2 * j + 1];
        if (acc) atomicOr(&s_or, 1);
        __syncthreads();
        if (threadIdx.x == 0) misc[1] = s_or;
    } else {
        // W f32 -> bf16 B-fragment order: frag f=kt*8+nt, lane l: n=l&15, k=(l>>4)*8+j
        int id = (blockIdx.x - 2) * 256 + threadIdx.x;       // 0..4095
        const float* W = (id < 2048) ? W1 : W2;
        bf16* Wsw = (id < 2048) ? Wsw1 : Wsw2;
        int t = id & 2047;
        int f = t >> 6, l = t & 63;
        int kt = f >> 3, nt = f & 7;
        int q = l >> 4, m = l & 15;
        bf16 tmp[8];
        #pragma unroll
        for (int j = 0; j < 8; ++j)
            tmp[j] = __float2bfloat16(W[(size_t)(kt * 32 + q * 8 + j) * DIM + nt * 16 + m]);
        *(bf16x8*)(Wsw + (size_t)t * 8) = *(const bf16x8*)tmp;
    }
}

// ============================ MFMA gemm (UNSCALED) ==========================
template <bool XF32>
__device__ __forceinline__ void gemm_body(const void* __restrict__ Xv,
                                          const bf16* __restrict__ Wsw,
                                          bf16* __restrict__ Y, int N,
                                          int gw, int nw, int lane,
                                          float* sld) {
    int m = lane & 15, q = lane >> 4;
    const bf16x8* bp = (const bf16x8*)Wsw;          // frag f at bp[f*64 + lane]
    for (int t = gw; t * 16 + 16 <= N; t += nw) {
        int base = t * 16;
        bf16x8 a[4];
        if (XF32) {
            const float* xp = (const float*)Xv + (size_t)(base + m) * DIM + q * 8;
            #pragma unroll
            for (int kt = 0; kt < 4; ++kt) {
                float4 v0 = *(const float4*)(xp + kt * 32);
                float4 v1 = *(const float4*)(xp + kt * 32 + 4);
                bf16 tt[8] = {__float2bfloat16(v0.x), __float2bfloat16(v0.y),
                              __float2bfloat16(v0.z), __float2bfloat16(v0.w),
                              __float2bfloat16(v1.x), __float2bfloat16(v1.y),
                              __float2bfloat16(v1.z), __float2bfloat16(v1.w)};
                a[kt] = *(const bf16x8*)tt;
            }
        } else {
            const bf16* xp = (const bf16*)Xv + (size_t)(base + m) * DIM + q * 8;
            #pragma unroll
            for (int kt = 0; kt < 4; ++kt)
                a[kt] = *(const bf16x8*)(xp + kt * 32);
        }
        f32x4 acc[8];
        #pragma unroll
        for (int nt = 0; nt < 8; ++nt) acc[nt] = (f32x4){0.f, 0.f, 0.f, 0.f};
        #pragma unroll
        for (int kt = 0; kt < 4; ++kt) {
            #pragma unroll
            for (int nt = 0; nt < 8; ++nt) {
                bf16x8 bfr = bp[(size_t)(kt * 8 + nt) * 64 + lane];
                acc[nt] = __builtin_amdgcn_mfma_f32_16x16x32_bf16(a[kt], bfr, acc[nt], 0, 0, 0);
            }
        }
        // D: row (node) = q*4 + r, col (channel) = nt*16 + m
        #pragma unroll
        for (int nt = 0; nt < 8; ++nt)
            #pragma unroll
            for (int r = 0; r < 4; ++r)
                sld[(q * 4 + r) * 132 + nt * 16 + m] = acc[nt][r];
        asm volatile("s_waitcnt lgkmcnt(0)" ::: "memory");
        #pragma unroll
        for (int i = 0; i < 4; ++i) {
            int row = i * 4 + q;
            const float* rp = sld + row * 132 + m * 8;
            float4 v0 = *(const float4*)rp;
            float4 v1 = *(const float4*)(rp + 4);
            alignas(16) bf16 tt[8] = {
                __float2bfloat16(v0.x), __float2bfloat16(v0.y),
                __float2bfloat16(v0.z), __float2bfloat16(v0.w),
                __float2bfloat16(v1.x), __float2bfloat16(v1.y),
                __float2bfloat16(v1.z), __float2bfloat16(v1.w)};
            *(uint4*)(Y + (size_t)(base + row) * DIM + m * 8) = *(const uint4*)tt;
        }
        asm volatile("s_waitcnt lgkmcnt(0)" ::: "memory");
    }
}

// ============================ K2: scatter || gemm1 ==========================
__global__ __launch_bounds__(256)
void scatter_gemm1(const int* __restrict__ ei, int E, const int* __restrict__ misc,
                   int* __restrict__ bcursor, unsigned* __restrict__ staged,
                   int nbuck, int nchunks,
                   const float* __restrict__ X, const bf16* __restrict__ Wsw,
                   bf16* __restrict__ Y, int N) {
    __shared__ float smem[4][16 * 132];             // 33.8 KB; scatter aliases it
    int bx = blockIdx.x;
    if (bx < nchunks) {
        int* s_cnt  = (int*)&smem[0][0];
        int* s_base = s_cnt + 512;
        int* s_fill = s_cnt + 1024;
        for (int i = threadIdx.x; i < nbuck; i += 256) { s_cnt[i] = 0; s_fill[i] = 0; }
        __syncthreads();
        int flagI = misc[1];
        int c0 = bx * CHUNK;
        int cn = min(E - c0, CHUNK);
        for (int i = threadIdx.x; i < cn; i += 256) {
            int e = c0 + i;
            int d = (flagI == 0) ? ei[2 * E + 2 * e] : ei[E + e];
            atomicAdd(&s_cnt[d >> 7], 1);
        }
        __syncthreads();
        for (int i = threadIdx.x; i < nbuck; i += 256) {
            int c = s_cnt[i];
            s_base[i] = c ? atomicAdd(&bcursor[i], c) : 0;
        }
        __syncthreads();
        for (int i = threadIdx.x; i < cn; i += 256) {
            int e = c0 + i;
            int s, d;
            if (flagI == 0) { s = ei[2 * e]; d = ei[2 * E + 2 * e]; }
            else            { s = ei[e];     d = ei[E + e]; }
            int b = d >> 7;
            int r = s_base[b] + atomicAdd(&s_fill[b], 1);
            if (r < (b + 1) * CAP)                           // overflow clamp (never hit)
                staged[r] = ((unsigned)s << 7) | (unsigned)(d & 127);
        }
    } else {
        int wid = threadIdx.x >> 6, lane = threadIdx.x & 63;
        int ngw = (gridDim.x - nchunks) * 4;
        gemm_body<true>(X, Wsw, Y, N, (bx - nchunks) * 4 + wid, ngw, lane, smem[wid]);
    }
}

// ================== K3: degree histogram -> dis; pre-scale Y1 ==============
// block per bucket: histogram staged dst -> dis = rsqrt(deg+1); then scale the
// bucket's own Y1 rows in place: Y1' = Y1 * dis  (removes all per-edge dis
// gathers/multiplies from both aggregate kernels).
__global__ __launch_bounds__(256)
void dis_scale(const unsigned* __restrict__ staged, const int* __restrict__ bcursor,
               float* __restrict__ dis, uint4* __restrict__ Y1, int N) {
    __shared__ int h[128];
    __shared__ float s_dis[128];
    int b = blockIdx.x, tid = threadIdx.x;
    if (tid < 128) h[tid] = 0;
    __syncthreads();
    int seg0 = b * CAP;
    int n = min(bcursor[b] - seg0, CAP);
    for (int i = tid; i < n; i += 256)
        atomicAdd(&h[staged[seg0 + i] & 127u], 1);
    __syncthreads();
    if (tid < 128) {
        float d = rsqrtf((float)(h[tid] + 1));
        s_dis[tid] = d;
        int node = b * 128 + tid;
        if (node < N) dis[node] = d;
    }
    __syncthreads();
    int base = b * 128;
    for (int idx = tid; idx < 2048; idx += 256) {       // 128 rows x 16 uint4
        int row = idx >> 4, c = idx & 15;
        int node = base + row;
        if (node >= N) continue;
        float d = s_dis[row];
        uint4 v = Y1[(size_t)node * 16 + c];
        alignas(16) bf16 t[8];
        t[0] = __float2bfloat16(__uint_as_float(v.x << 16) * d);
        t[1] = __float2bfloat16(__uint_as_float(v.x & 0xffff0000u) * d);
        t[2] = __float2bfloat16(__uint_as_float(v.y << 16) * d);
        t[3] = __float2bfloat16(__uint_as_float(v.y & 0xffff0000u) * d);
        t[4] = __float2bfloat16(__uint_as_float(v.z << 16) * d);
        t[5] = __float2bfloat16(__uint_as_float(v.z & 0xffff0000u) * d);
        t[6] = __float2bfloat16(__uint_as_float(v.w << 16) * d);
        t[7] = __float2bfloat16(__uint_as_float(v.w & 0xffff0000u) * d);
        Y1[(size_t)node * 16 + c] = *(const uint4*)t;
    }
}

// ============================ helpers =======================================
__device__ __forceinline__ void unpack8(const uint4& v, float* f) {
    f[0] = __uint_as_float(v.x << 16);
    f[1] = __uint_as_float(v.x & 0xffff0000u);
    f[2] = __uint_as_float(v.y << 16);
    f[3] = __uint_as_float(v.y & 0xffff0000u);
    f[4] = __uint_as_float(v.z << 16);
    f[5] = __uint_as_float(v.z & 0xffff0000u);
    f[6] = __uint_as_float(v.w << 16);
    f[7] = __uint_as_float(v.w & 0xffff0000u);
}

// Edge-parallel accumulation into transposed-column LDS tile.
// Element (row, c) lives at accT[row*132 + (c&7)*16 + (c>>3)] so the 16 lanes
// of a group (contiguous channels) spread over 16 banks, and the +4r row term
// staggers groups. Random dst order in staged => negligible same-address runs.
__device__ __forceinline__ void edge_accum(float* accT, const uint4* __restrict__ Y,
                                           const unsigned* __restrict__ staged,
                                           int seg0, int n, int g, int cl) {
    int e = g;
    while (e + 32 * 7 < n) {
        unsigned p[8];
        #pragma unroll
        for (int u = 0; u < 8; ++u) p[u] = staged[seg0 + e + 32 * u];
        uint4 v[8];
        #pragma unroll
        for (int u = 0; u < 8; ++u) v[u] = Y[(size_t)(p[u] >> 7) * 16 + cl];
        #pragma unroll
        for (int u = 0; u < 8; ++u) {
            float f[8]; unpack8(v[u], f);
            float* ap = accT + (p[u] & 127u) * 132 + cl;
            #pragma unroll
            for (int j = 0; j < 8; ++j) unsafeAtomicAdd(ap + j * 16, f[j]);
        }
        e += 256;
    }
    for (; e < n; e += 32) {
        unsigned p = staged[seg0 + e];
        uint4 v = Y[(size_t)(p >> 7) * 16 + cl];
        float f[8]; unpack8(v, f);
        float* ap = accT + (p & 127u) * 132 + cl;
        #pragma unroll
        for (int j = 0; j < 8; ++j) unsafeAtomicAdd(ap + j * 16, f[j]);
    }
}

// ================= K4: bucket aggregate1 + gemm2 (fused) ====================
// P1: edge-parallel sum of pre-scaled Y1' rows into LDS f32 tile
// P2: h = relu(dn*(sum + Y1'[n]) + b1) -> regs -> bf16 LDS tile (aliased)
// P4: 128x128 @ 128x128 MFMA, epilogue staged in LDS (aliased), pre-scaled
//     Y2' = bf16(h@W2 * dn) coalesced store.
__global__ __launch_bounds__(512, 4)
void agg1_gemm2_bucket(const uint4* __restrict__ Y, const unsigned* __restrict__ staged,
                       const int* __restrict__ bcursor, const float* __restrict__ dis,
                       const float* __restrict__ bias, const bf16* __restrict__ Wsw,
                       bf16* __restrict__ Y2, int N) {
    __shared__ float accT[128 * 132];           // 67.6 KB; re-used by hT and s_out
    bf16* hT = (bf16*)accT;                     // [128][136] bf16 (34.8 KB)
    int tid = threadIdx.x;
    int b = blockIdx.x;
    int seg0 = b * CAP, base = b * 128;
    int n = min(bcursor[b] - seg0, CAP);

    f32x4* az = (f32x4*)accT;
    for (int i = tid; i < 128 * 132 / 4; i += 512) az[i] = (f32x4){0.f, 0.f, 0.f, 0.f};
    __syncthreads();

    edge_accum(accT, Y, staged, seg0, n, tid >> 4, tid & 15);
    __syncthreads();

    // ---- readout to registers ----
    bf16x8 hreg[4];
    #pragma unroll
    for (int it = 0; it < 4; ++it) {
        int idx = tid + 512 * it;               // 0..2047
        int row = idx >> 4, t = idx & 15;
        int node = base + row;
        alignas(16) bf16 hh[8] = {};
        if (node < N) {
            float dn = dis[node];
            uint4 sv = Y[(size_t)node * 16 + t];
            float f[8]; unpack8(sv, f);
            float4 b0 = ((const float4*)bias)[2 * t];
            float4 b1v = ((const float4*)bias)[2 * t + 1];
            float bb[8] = {b0.x, b0.y, b0.z, b0.w, b1v.x, b1v.y, b1v.z, b1v.w};
            #pragma unroll
            for (int j = 0; j < 8; ++j) {
                float sum = accT[row * 132 + j * 16 + t] + f[j];   // Y1' pre-scaled
                hh[j] = __float2bfloat16(fmaxf(dn * sum + bb[j], 0.f));
            }
        }
        hreg[it] = *(const bf16x8*)hh;
    }
    __syncthreads();
    #pragma unroll
    for (int it = 0; it < 4; ++it) {
        int idx = tid + 512 * it;
        int row = idx >> 4, t = idx & 15;
        *(bf16x8*)&hT[(size_t)row * 136 + t * 8] = hreg[it];
    }
    __syncthreads();

    // ---- MFMA: wave w computes rows w*16..w*16+15, all 128 cols ----
    int wave = tid >> 6, lane = tid & 63;
    int m = lane & 15, q = lane >> 4;
    bf16x8 a[4];
    #pragma unroll
    for (int kt = 0; kt < 4; ++kt)
        a[kt] = *(const bf16x8*)&hT[(size_t)(wave * 16 + m) * 136 + q * 8 + kt * 32];
    __syncthreads();                            // hT dead; s_out may overwrite

    const bf16x8* bp = (const bf16x8*)Wsw;
    f32x4 acc[8];
    #pragma unroll
    for (int nt = 0; nt < 8; ++nt) acc[nt] = (f32x4){0.f, 0.f, 0.f, 0.f};
    #pragma unroll
    for (int kt = 0; kt < 4; ++kt)
        #pragma unroll
        for (int nt = 0; nt < 8; ++nt) {
            bf16x8 bfr = bp[(size_t)(kt * 8 + nt) * 64 + lane];
            acc[nt] = __builtin_amdgcn_mfma_f32_16x16x32_bf16(a[kt], bfr, acc[nt], 0, 0, 0);
        }
    float* s_out = accT + wave * (16 * 132);
    #pragma unroll
    for (int nt = 0; nt < 8; ++nt)
        #pragma unroll
        for (int r = 0; r < 4; ++r)
            s_out[(q * 4 + r) * 132 + nt * 16 + m] = acc[nt][r];
    asm volatile("s_waitcnt lgkmcnt(0)" ::: "memory");
    #pragma unroll
    for (int i = 0; i < 4; ++i) {
        int row = i * 4 + q;
        int node = base + wave * 16 + row;
        if (node < N) {
            float ds = dis[node];
            const float* rp = s_out + row * 132 + m * 8;
            float4 v0 = *(const float4*)rp;
            float4 v1 = *(const float4*)(rp + 4);
            alignas(16) bf16 tt[8] = {
                __float2bfloat16(v0.x * ds), __float2bfloat16(v0.y * ds),
                __float2bfloat16(v0.z * ds), __float2bfloat16(v0.w * ds),
                __float2bfloat16(v1.x * ds), __float2bfloat16(v1.y * ds),
                __float2bfloat16(v1.z * ds), __float2bfloat16(v1.w * ds)};
            *(uint4*)(Y2 + (size_t)node * DIM + m * 8) = *(const uint4*)tt;
        }
    }
}

// ================= K5: bucket aggregate2 (inputs pre-scaled) ================
__global__ __launch_bounds__(512, 4)
void agg2_bucket(const uint4* __restrict__ Y, const unsigned* __restrict__ staged,
                 const int* __restrict__ bcursor, const float* __restrict__ dis,
                 const float* __restrict__ bias, float4* __restrict__ Of, int N) {
    __shared__ float accT[128 * 132];
    int tid = threadIdx.x;
    int b = blockIdx.x;
    int seg0 = b * CAP, base = b * 128;
    int n = min(bcursor[b] - seg0, CAP);

    f32x4* az = (f32x4*)accT;
    for (int i = tid; i < 128 * 132 / 4; i += 512) az[i] = (f32x4){0.f, 0.f, 0.f, 0.f};
    __syncthreads();

    edge_accum(accT, Y, staged, seg0, n, tid >> 4, tid & 15);
    __syncthreads();

    #pragma unroll
    for (int it = 0; it < 4; ++it) {
        int idx = tid + 512 * it;
        int row = idx >> 4, t = idx & 15;
        int node = base + row;
        if (node >= N) continue;
        float dn = dis[node];
        uint4 sv = Y[(size_t)node * 16 + t];
        float f[8]; unpack8(sv, f);
        float4 b0 = ((const float4*)bias)[2 * t];
        float4 b1v = ((const float4*)bias)[2 * t + 1];
        float bb[8] = {b0.x, b0.y, b0.z, b0.w, b1v.x, b1v.y, b1v.z, b1v.w};
        float o[8];
        #pragma unroll
        for (int j = 0; j < 8; ++j) {
            float sum = accT[row * 132 + j * 16 + t] + f[j];     // Y2' pre-scaled
            o[j] = fmaxf(dn * sum + bb[j], 0.f);
        }
        Of[(size_t)node * 32 + 2 * t]     = make_float4(o[0], o[1], o[2], o[3]);
        Of[(size_t)node * 32 + 2 * t + 1] = make_float4(o[4], o[5], o[6], o[7]);
    }
}

// ============================ launcher ======================================
extern "C" void kernel_launch(void* const* d_in, const int* in_sizes, int n_in,
                              void* d_out, int out_size, void* d_ws, size_t ws_size,
                              hipStream_t stream) {
    const float* x  = (const float*)d_in[0];
    const int*   ei = (const int*)d_in[1];
    const float* W1 = (const float*)d_in[2];
    const float* b1 = (const float*)d_in[3];
    const float* W2 = (const float*)d_in[4];
    const float* b2 = (const float*)d_in[5];

    int N = in_sizes[0] / DIM;      // 50000
    int E = in_sizes[1] / 2;        // 600000
    int nbuck = (N + 127) / 128;    // 391
    int nchunks = (E + CHUNK - 1) / CHUNK;  // 147

    char* w = (char*)d_ws;
    size_t used = 0;
    auto carve = [&](size_t bytes) {
        char* p = w + used;
        used += (bytes + 255) & ~(size_t)255;
        return p;
    };
    int*      misc     = (int*)     carve(256);              // [1]=flagI
    int*      bcursor  = (int*)     carve((size_t)(nbuck + 1) * 4);
    unsigned* staged   = (unsigned*)carve((size_t)nbuck * CAP * 4);   // 6.4 MB
    float*    dis      = (float*)   carve((size_t)N * 4);
    bf16*     ybuf     = (bf16*)    carve((size_t)N * DIM * 2);       // Y1, then Y1'
    bf16*     hbuf     = (bf16*)    carve((size_t)N * DIM * 2);       // Y2'
    bf16*     Wsw1     = (bf16*)    carve((size_t)DIM * DIM * 2);
    bf16*     Wsw2     = (bf16*)    carve((size_t)DIM * DIM * 2);

    prep_kernel <<<18, 256, 0, stream>>>(bcursor, nbuck, ei, E, misc, W1, W2, Wsw1, Wsw2);
    scatter_gemm1<<<nchunks + 784, 256, 0, stream>>>(ei, E, misc, bcursor, staged,
                                                     nbuck, nchunks, x, Wsw1, ybuf, N);
    dis_scale<<<nbuck, 256, 0, stream>>>(staged, bcursor, dis, (uint4*)ybuf, N);
    agg1_gemm2_bucket<<<nbuck, 512, 0, stream>>>((const uint4*)ybuf, staged, bcursor,
                                                 dis, b1, Wsw2, hbuf, N);
    agg2_bucket<<<nbuck, 512, 0, stream>>>((const uint4*)hbuf, staged, bcursor,
                                           dis, b2, (float4*)d_out, N);
}

// Round 4
// 1171.629 us; speedup vs baseline: 1.0008x; 1.0008x over previous
//
#include <hip/hip_runtime.h>
#include <hip/hip_bf16.h>

#define DIM 128
#define CHUNK 4096
#define CAP 4096        // slab capacity per 128-node bucket (65 sigma above mean)
typedef __hip_bfloat16 bf16;
typedef __attribute__((ext_vector_type(8))) short bf16x8;   // 8 bf16 = 4 VGPRs
typedef __attribute__((ext_vector_type(4))) float f32x4;

// ============================ K1: prep ======================================
__global__ void prep_kernel(int* __restrict__ bcursor, int nbuck,
                            const int* __restrict__ ei, int E, int* __restrict__ misc,
                            const float* __restrict__ W1, const float* __restrict__ W2,
                            bf16* __restrict__ Wsw1, bf16* __restrict__ Wsw2) {
    if (blockIdx.x == 0) {
        for (int i = threadIdx.x; i < nbuck; i += 256) bcursor[i] = i * CAP;
    } else if (blockIdx.x == 1) {
        __shared__ int s_or;
        if (threadIdx.x == 0) s_or = 0;
        __syncthreads();
        int lim = E < 16384 ? E : 16384;
        int acc = 0;
        for (int j = threadIdx.x; j < lim; j += 256) acc |= ei[2 * j + 1];
        if (acc) atomicOr(&s_or, 1);
        __syncthreads();
        if (threadIdx.x == 0) misc[1] = s_or;
    } else {
        // W f32 -> bf16 B-fragment order: frag f=kt*8+nt, lane l: n=l&15, k=(l>>4)*8+j
        int id = (blockIdx.x - 2) * 256 + threadIdx.x;       // 0..4095
        const float* W = (id < 2048) ? W1 : W2;
        bf16* Wsw = (id < 2048) ? Wsw1 : Wsw2;
        int t = id & 2047;
        int f = t >> 6, l = t & 63;
        int kt = f >> 3, nt = f & 7;
        int q = l >> 4, m = l & 15;
        bf16 tmp[8];
        #pragma unroll
        for (int j = 0; j < 8; ++j)
            tmp[j] = __float2bfloat16(W[(size_t)(kt * 32 + q * 8 + j) * DIM + nt * 16 + m]);
        *(bf16x8*)(Wsw + (size_t)t * 8) = *(const bf16x8*)tmp;
    }
}

// ============================ MFMA gemm (UNSCALED) ==========================
template <bool XF32>
__device__ __forceinline__ void gemm_body(const void* __restrict__ Xv,
                                          const bf16* __restrict__ Wsw,
                                          bf16* __restrict__ Y, int N,
                                          int gw, int nw, int lane,
                                          float* sld) {
    int m = lane & 15, q = lane >> 4;
    const bf16x8* bp = (const bf16x8*)Wsw;          // frag f at bp[f*64 + lane]
    for (int t = gw; t * 16 + 16 <= N; t += nw) {
        int base = t * 16;
        bf16x8 a[4];
        if (XF32) {
            const float* xp = (const float*)Xv + (size_t)(base + m) * DIM + q * 8;
            #pragma unroll
            for (int kt = 0; kt < 4; ++kt) {
                float4 v0 = *(const float4*)(xp + kt * 32);
                float4 v1 = *(const float4*)(xp + kt * 32 + 4);
                bf16 tt[8] = {__float2bfloat16(v0.x), __float2bfloat16(v0.y),
                              __float2bfloat16(v0.z), __float2bfloat16(v0.w),
                              __float2bfloat16(v1.x), __float2bfloat16(v1.y),
                              __float2bfloat16(v1.z), __float2bfloat16(v1.w)};
                a[kt] = *(const bf16x8*)tt;
            }
        } else {
            const bf16* xp = (const bf16*)Xv + (size_t)(base + m) * DIM + q * 8;
            #pragma unroll
            for (int kt = 0; kt < 4; ++kt)
                a[kt] = *(const bf16x8*)(xp + kt * 32);
        }
        f32x4 acc[8];
        #pragma unroll
        for (int nt = 0; nt < 8; ++nt) acc[nt] = (f32x4){0.f, 0.f, 0.f, 0.f};
        #pragma unroll
        for (int kt = 0; kt < 4; ++kt) {
            #pragma unroll
            for (int nt = 0; nt < 8; ++nt) {
                bf16x8 bfr = bp[(size_t)(kt * 8 + nt) * 64 + lane];
                acc[nt] = __builtin_amdgcn_mfma_f32_16x16x32_bf16(a[kt], bfr, acc[nt], 0, 0, 0);
            }
        }
        // D: row (node) = q*4 + r, col (channel) = nt*16 + m
        #pragma unroll
        for (int nt = 0; nt < 8; ++nt)
            #pragma unroll
            for (int r = 0; r < 4; ++r)
                sld[(q * 4 + r) * 132 + nt * 16 + m] = acc[nt][r];
        asm volatile("s_waitcnt lgkmcnt(0)" ::: "memory");
        #pragma unroll
        for (int i = 0; i < 4; ++i) {
            int row = i * 4 + q;
            const float* rp = sld + row * 132 + m * 8;
            float4 v0 = *(const float4*)rp;
            float4 v1 = *(const float4*)(rp + 4);
            alignas(16) bf16 tt[8] = {
                __float2bfloat16(v0.x), __float2bfloat16(v0.y),
                __float2bfloat16(v0.z), __float2bfloat16(v0.w),
                __float2bfloat16(v1.x), __float2bfloat16(v1.y),
                __float2bfloat16(v1.z), __float2bfloat16(v1.w)};
            *(uint4*)(Y + (size_t)(base + row) * DIM + m * 8) = *(const uint4*)tt;
        }
        asm volatile("s_waitcnt lgkmcnt(0)" ::: "memory");
    }
}

// ============================ K2: scatter || gemm1 ==========================
__global__ __launch_bounds__(256)
void scatter_gemm1(const int* __restrict__ ei, int E, const int* __restrict__ misc,
                   int* __restrict__ bcursor, unsigned* __restrict__ staged,
                   int nbuck, int nchunks,
                   const float* __restrict__ X, const bf16* __restrict__ Wsw,
                   bf16* __restrict__ Y, int N) {
    __shared__ float smem[4][16 * 132];             // 33.8 KB; scatter aliases it
    int bx = blockIdx.x;
    if (bx < nchunks) {
        int* s_cnt  = (int*)&smem[0][0];
        int* s_base = s_cnt + 512;
        int* s_fill = s_cnt + 1024;
        for (int i = threadIdx.x; i < nbuck; i += 256) { s_cnt[i] = 0; s_fill[i] = 0; }
        __syncthreads();
        int flagI = misc[1];
        int c0 = bx * CHUNK;
        int cn = min(E - c0, CHUNK);
        for (int i = threadIdx.x; i < cn; i += 256) {
            int e = c0 + i;
            int d = (flagI == 0) ? ei[2 * E + 2 * e] : ei[E + e];
            atomicAdd(&s_cnt[d >> 7], 1);
        }
        __syncthreads();
        for (int i = threadIdx.x; i < nbuck; i += 256) {
            int c = s_cnt[i];
            s_base[i] = c ? atomicAdd(&bcursor[i], c) : 0;
        }
        __syncthreads();
        for (int i = threadIdx.x; i < cn; i += 256) {
            int e = c0 + i;
            int s, d;
            if (flagI == 0) { s = ei[2 * e]; d = ei[2 * E + 2 * e]; }
            else            { s = ei[e];     d = ei[E + e]; }
            int b = d >> 7;
            int r = s_base[b] + atomicAdd(&s_fill[b], 1);
            if (r < (b + 1) * CAP)                           // overflow clamp (never hit)
                staged[r] = ((unsigned)s << 7) | (unsigned)(d & 127);
        }
    } else {
        int wid = threadIdx.x >> 6, lane = threadIdx.x & 63;
        int ngw = (gridDim.x - nchunks) * 4;
        gemm_body<true>(X, Wsw, Y, N, (bx - nchunks) * 4 + wid, ngw, lane, smem[wid]);
    }
}

// ================== K3: degree histogram -> dis; pre-scale Y1 ==============
__global__ __launch_bounds__(256)
void dis_scale(const unsigned* __restrict__ staged, const int* __restrict__ bcursor,
               float* __restrict__ dis, uint4* __restrict__ Y1, int N) {
    __shared__ int h[128];
    __shared__ float s_dis[128];
    int b = blockIdx.x, tid = threadIdx.x;
    if (tid < 128) h[tid] = 0;
    __syncthreads();
    int seg0 = b * CAP;
    int n = min(bcursor[b] - seg0, CAP);
    for (int i = tid; i < n; i += 256)
        atomicAdd(&h[staged[seg0 + i] & 127u], 1);
    __syncthreads();
    if (tid < 128) {
        float d = rsqrtf((float)(h[tid] + 1));
        s_dis[tid] = d;
        int node = b * 128 + tid;
        if (node < N) dis[node] = d;
    }
    __syncthreads();
    int base = b * 128;
    for (int idx = tid; idx < 2048; idx += 256) {       // 128 rows x 16 uint4
        int row = idx >> 4, c = idx & 15;
        int node = base + row;
        if (node >= N) continue;
        float d = s_dis[row];
        uint4 v = Y1[(size_t)node * 16 + c];
        alignas(16) bf16 t[8];
        t[0] = __float2bfloat16(__uint_as_float(v.x << 16) * d);
        t[1] = __float2bfloat16(__uint_as_float(v.x & 0xffff0000u) * d);
        t[2] = __float2bfloat16(__uint_as_float(v.y << 16) * d);
        t[3] = __float2bfloat16(__uint_as_float(v.y & 0xffff0000u) * d);
        t[4] = __float2bfloat16(__uint_as_float(v.z << 16) * d);
        t[5] = __float2bfloat16(__uint_as_float(v.z & 0xffff0000u) * d);
        t[6] = __float2bfloat16(__uint_as_float(v.w << 16) * d);
        t[7] = __float2bfloat16(__uint_as_float(v.w & 0xffff0000u) * d);
        Y1[(size_t)node * 16 + c] = *(const uint4*)t;
    }
}

// ============================ helpers =======================================
__device__ __forceinline__ void unpack8(const uint4& v, float* f) {
    f[0] = __uint_as_float(v.x << 16);
    f[1] = __uint_as_float(v.x & 0xffff0000u);
    f[2] = __uint_as_float(v.y << 16);
    f[3] = __uint_as_float(v.y & 0xffff0000u);
    f[4] = __uint_as_float(v.z << 16);
    f[5] = __uint_as_float(v.z & 0xffff0000u);
    f[6] = __uint_as_float(v.w << 16);
    f[7] = __uint_as_float(v.w & 0xffff0000u);
}

// Native LDS float atomic: 8 channels at addr + j*64B (j*16 floats), relaxed,
// no-return ds_add_f32. addr = low 32 bits of the generic shared pointer
// (= LDS byte offset; shared aperture encodes offset in the low word).
__device__ __forceinline__ void ds_add8(const float* p, const float* f) {
    unsigned a0 = (unsigned)(uintptr_t)p;
    asm volatile(
        "ds_add_f32 %0, %1\n\t"
        "ds_add_f32 %0, %2 offset:64\n\t"
        "ds_add_f32 %0, %3 offset:128\n\t"
        "ds_add_f32 %0, %4 offset:192\n\t"
        "ds_add_f32 %0, %5 offset:256\n\t"
        "ds_add_f32 %0, %6 offset:320\n\t"
        "ds_add_f32 %0, %7 offset:384\n\t"
        "ds_add_f32 %0, %8 offset:448"
        :: "v"(a0), "v"(f[0]), "v"(f[1]), "v"(f[2]), "v"(f[3]),
           "v"(f[4]), "v"(f[5]), "v"(f[6]), "v"(f[7]));
}

// ================= K4: bucket aggregate1 + gemm2 (fused) ====================
// P1: edge-parallel sum of pre-scaled Y1' rows into LDS f32 tile (ds_add_f32)
// P2: h = relu(dn*(sum + Y1'[n]) + b1) -> regs -> bf16 LDS tile (aliased)
// P3: 128x128 @ 128x128 MFMA, epilogue staged in LDS (aliased), pre-scaled
//     Y2' = bf16(h@W2 * dn) coalesced store.
__global__ __launch_bounds__(512, 4)
void agg1_gemm2_bucket(const uint4* __restrict__ Y, const unsigned* __restrict__ staged,
                       const int* __restrict__ bcursor, const float* __restrict__ dis,
                       const float* __restrict__ bias, const bf16* __restrict__ Wsw,
                       bf16* __restrict__ Y2, int N) {
    __shared__ float accT[128 * 132];           // 67.6 KB; re-used by hT and s_out
    bf16* hT = (bf16*)accT;                     // [128][136] bf16 (34.8 KB)
    int tid = threadIdx.x;
    int b = blockIdx.x;
    int seg0 = b * CAP, base = b * 128;
    int n = min(bcursor[b] - seg0, CAP);

    f32x4* az = (f32x4*)accT;
    for (int i = tid; i < 128 * 132 / 4; i += 512) az[i] = (f32x4){0.f, 0.f, 0.f, 0.f};
    __syncthreads();

    // ---- edge-parallel accumulation; element (row,c) at row*132+(c&7)*16+(c>>3)
    {
        int g = tid >> 4, cl = tid & 15;
        int e = g;
        while (e + 32 * 7 < n) {
            unsigned p[8];
            #pragma unroll
            for (int u = 0; u < 8; ++u) p[u] = staged[seg0 + e + 32 * u];
            uint4 v[8];
            #pragma unroll
            for (int u = 0; u < 8; ++u) v[u] = Y[(size_t)(p[u] >> 7) * 16 + cl];
            #pragma unroll
            for (int u = 0; u < 8; ++u) {
                float f[8]; unpack8(v[u], f);
                ds_add8(&accT[(p[u] & 127u) * 132 + cl], f);
            }
            e += 256;
        }
        for (; e < n; e += 32) {
            unsigned p = staged[seg0 + e];
            uint4 v = Y[(size_t)(p >> 7) * 16 + cl];
            float f[8]; unpack8(v, f);
            ds_add8(&accT[(p & 127u) * 132 + cl], f);
        }
    }
    asm volatile("s_waitcnt lgkmcnt(0)" ::: "memory");  // asm ds ops invisible to compiler
    __syncthreads();

    // ---- readout to registers ----
    bf16x8 hreg[4];
    #pragma unroll
    for (int it = 0; it < 4; ++it) {
        int idx = tid + 512 * it;               // 0..2047
        int row = idx >> 4, t = idx & 15;
        int node = base + row;
        alignas(16) bf16 hh[8] = {};
        if (node < N) {
            float dn = dis[node];
            uint4 sv = Y[(size_t)node * 16 + t];
            float f[8]; unpack8(sv, f);
            float4 b0 = ((const float4*)bias)[2 * t];
            float4 b1v = ((const float4*)bias)[2 * t + 1];
            float bb[8] = {b0.x, b0.y, b0.z, b0.w, b1v.x, b1v.y, b1v.z, b1v.w};
            #pragma unroll
            for (int j = 0; j < 8; ++j) {
                float sum = accT[row * 132 + j * 16 + t] + f[j];   // Y1' pre-scaled
                hh[j] = __float2bfloat16(fmaxf(dn * sum + bb[j], 0.f));
            }
        }
        hreg[it] = *(const bf16x8*)hh;
    }
    __syncthreads();
    #pragma unroll
    for (int it = 0; it < 4; ++it) {
        int idx = tid + 512 * it;
        int row = idx >> 4, t = idx & 15;
        *(bf16x8*)&hT[(size_t)row * 136 + t * 8] = hreg[it];
    }
    __syncthreads();

    // ---- MFMA: wave w computes rows w*16..w*16+15, all 128 cols ----
    int wave = tid >> 6, lane = tid & 63;
    int m = lane & 15, q = lane >> 4;
    bf16x8 a[4];
    #pragma unroll
    for (int kt = 0; kt < 4; ++kt)
        a[kt] = *(const bf16x8*)&hT[(size_t)(wave * 16 + m) * 136 + q * 8 + kt * 32];
    __syncthreads();                            // hT dead; s_out may overwrite

    const bf16x8* bp = (const bf16x8*)Wsw;
    f32x4 acc[8];
    #pragma unroll
    for (int nt = 0; nt < 8; ++nt) acc[nt] = (f32x4){0.f, 0.f, 0.f, 0.f};
    #pragma unroll
    for (int kt = 0; kt < 4; ++kt)
        #pragma unroll
        for (int nt = 0; nt < 8; ++nt) {
            bf16x8 bfr = bp[(size_t)(kt * 8 + nt) * 64 + lane];
            acc[nt] = __builtin_amdgcn_mfma_f32_16x16x32_bf16(a[kt], bfr, acc[nt], 0, 0, 0);
        }
    float* s_out = accT + wave * (16 * 132);
    #pragma unroll
    for (int nt = 0; nt < 8; ++nt)
        #pragma unroll
        for (int r = 0; r < 4; ++r)
            s_out[(q * 4 + r) * 132 + nt * 16 + m] = acc[nt][r];
    asm volatile("s_waitcnt lgkmcnt(0)" ::: "memory");
    #pragma unroll
    for (int i = 0; i < 4; ++i) {
        int row = i * 4 + q;
        int node = base + wave * 16 + row;
        if (node < N) {
            float ds = dis[node];
            const float* rp = s_out + row * 132 + m * 8;
            float4 v0 = *(const float4*)rp;
            float4 v1 = *(const float4*)(rp + 4);
            alignas(16) bf16 tt[8] = {
                __float2bfloat16(v0.x * ds), __float2bfloat16(v0.y * ds),
                __float2bfloat16(v0.z * ds), __float2bfloat16(v0.w * ds),
                __float2bfloat16(v1.x * ds), __float2bfloat16(v1.y * ds),
                __float2bfloat16(v1.z * ds), __float2bfloat16(v1.w * ds)};
            *(uint4*)(Y2 + (size_t)node * DIM + m * 8) = *(const uint4*)tt;
        }
    }
}

// ================= K5: bucket aggregate2 (inputs pre-scaled) ================
__global__ __launch_bounds__(512, 4)
void agg2_bucket(const uint4* __restrict__ Y, const unsigned* __restrict__ staged,
                 const int* __restrict__ bcursor, const float* __restrict__ dis,
                 const float* __restrict__ bias, float4* __restrict__ Of, int N) {
    __shared__ float accT[128 * 132];
    int tid = threadIdx.x;
    int b = blockIdx.x;
    int seg0 = b * CAP, base = b * 128;
    int n = min(bcursor[b] - seg0, CAP);

    f32x4* az = (f32x4*)accT;
    for (int i = tid; i < 128 * 132 / 4; i += 512) az[i] = (f32x4){0.f, 0.f, 0.f, 0.f};
    __syncthreads();

    {
        int g = tid >> 4, cl = tid & 15;
        int e = g;
        while (e + 32 * 7 < n) {
            unsigned p[8];
            #pragma unroll
            for (int u = 0; u < 8; ++u) p[u] = staged[seg0 + e + 32 * u];
            uint4 v[8];
            #pragma unroll
            for (int u = 0; u < 8; ++u) v[u] = Y[(size_t)(p[u] >> 7) * 16 + cl];
            #pragma unroll
            for (int u = 0; u < 8; ++u) {
                float f[8]; unpack8(v[u], f);
                ds_add8(&accT[(p[u] & 127u) * 132 + cl], f);
            }
            e += 256;
        }
        for (; e < n; e += 32) {
            unsigned p = staged[seg0 + e];
            uint4 v = Y[(size_t)(p >> 7) * 16 + cl];
            float f[8]; unpack8(v, f);
            ds_add8(&accT[(p & 127u) * 132 + cl], f);
        }
    }
    asm volatile("s_waitcnt lgkmcnt(0)" ::: "memory");
    __syncthreads();

    #pragma unroll
    for (int it = 0; it < 4; ++it) {
        int idx = tid + 512 * it;
        int row = idx >> 4, t = idx & 15;
        int node = base + row;
        if (node >= N) continue;
        float dn = dis[node];
        uint4 sv = Y[(size_t)node * 16 + t];
        float f[8]; unpack8(sv, f);
        float4 b0 = ((const float4*)bias)[2 * t];
        float4 b1v = ((const float4*)bias)[2 * t + 1];
        float bb[8] = {b0.x, b0.y, b0.z, b0.w, b1v.x, b1v.y, b1v.z, b1v.w};
        float o[8];
        #pragma unroll
        for (int j = 0; j < 8; ++j) {
            float sum = accT[row * 132 + j * 16 + t] + f[j];     // Y2' pre-scaled
            o[j] = fmaxf(dn * sum + bb[j], 0.f);
        }
        Of[(size_t)node * 32 + 2 * t]     = make_float4(o[0], o[1], o[2], o[3]);
        Of[(size_t)node * 32 + 2 * t + 1] = make_float4(o[4], o[5], o[6], o[7]);
    }
}

// ============================ launcher ======================================
extern "C" void kernel_launch(void* const* d_in, const int* in_sizes, int n_in,
                              void* d_out, int out_size, void* d_ws, size_t ws_size,
                              hipStream_t stream) {
    const float* x  = (const float*)d_in[0];
    const int*   ei = (const int*)d_in[1];
    const float* W1 = (const float*)d_in[2];
    const float* b1 = (const float*)d_in[3];
    const float* W2 = (const float*)d_in[4];
    const float* b2 = (const float*)d_in[5];

    int N = in_sizes[0] / DIM;      // 50000
    int E = in_sizes[1] / 2;        // 600000
    int nbuck = (N + 127) / 128;    // 391
    int nchunks = (E + CHUNK - 1) / CHUNK;  // 147

    char* w = (char*)d_ws;
    size_t used = 0;
    auto carve = [&](size_t bytes) {
        char* p = w + used;
        used += (bytes + 255) & ~(size_t)255;
        return p;
    };
    int*      misc     = (int*)     carve(256);              // [1]=flagI
    int*      bcursor  = (int*)     carve((size_t)(nbuck + 1) * 4);
    unsigned* staged   = (unsigned*)carve((size_t)nbuck * CAP * 4);   // 6.4 MB
    float*    dis      = (float*)   carve((size_t)N * 4);
    bf16*     ybuf     = (bf16*)    carve((size_t)N * DIM * 2);       // Y1, then Y1'
    bf16*     hbuf     = (bf16*)    carve((size_t)N * DIM * 2);       // Y2'
    bf16*     Wsw1     = (bf16*)    carve((size_t)DIM * DIM * 2);
    bf16*     Wsw2     = (bf16*)    carve((size_t)DIM * DIM * 2);

    prep_kernel <<<18, 256, 0, stream>>>(bcursor, nbuck, ei, E, misc, W1, W2, Wsw1, Wsw2);
    scatter_gemm1<<<nchunks + 784, 256, 0, stream>>>(ei, E, misc, bcursor, staged,
                                                     nbuck, nchunks, x, Wsw1, ybuf, N);
    dis_scale<<<nbuck, 256, 0, stream>>>(staged, bcursor, dis, (uint4*)ybuf, N);
    agg1_gemm2_bucket<<<nbuck, 512, 0, stream>>>((const uint4*)ybuf, staged, bcursor,
                                                 dis, b1, Wsw2, hbuf, N);
    agg2_bucket<<<nbuck, 512, 0, stream>>>((const uint4*)hbuf, staged, bcursor,
                                           dis, b2, (float4*)d_out, N);
}

// Round 6
// 211.335 us; speedup vs baseline: 5.5485x; 5.5439x over previous
//
#include <hip/hip_runtime.h>
#include <hip/hip_bf16.h>

#define DIM 128
#define CHUNK 4096
#define CAP 4096        // slab capacity per 128-node bucket (65 sigma above mean)
typedef __hip_bfloat16 bf16;
typedef __attribute__((ext_vector_type(8))) short bf16x8;   // 8 bf16 = 4 VGPRs
typedef __attribute__((ext_vector_type(4))) float f32x4;

// ===================== K0: detect int width + zero deg ======================
// b0: flagI detect (0 -> int64 layout); b1..: zero cnt[] (workspace is poisoned
// between replays, so cnt must be re-zeroed every launch).
__global__ void detect_zero(const int* __restrict__ ei, int E, int* __restrict__ misc,
                            int* __restrict__ cnt, int N) {
    if (blockIdx.x == 0) {
        __shared__ int s_or;
        if (threadIdx.x == 0) s_or = 0;
        __syncthreads();
        int lim = E < 16384 ? E : 16384;
        int acc = 0;
        for (int j = threadIdx.x; j < lim; j += 256) acc |= ei[2 * j + 1];
        if (acc) atomicOr(&s_or, 1);
        __syncthreads();
        if (threadIdx.x == 0) misc[1] = s_or;
    } else {
        int i = (blockIdx.x - 1) * 256 + threadIdx.x;
        if (i < N) cnt[i] = 0;
    }
}

// ============ K1: cursors + W swizzle + degree histogram ====================
// b0: slab cursors; b1..16: W f32 -> bf16 B-fragment swizzle; b17..80: degree
// atomics over the edge dst column (flagI from previous dispatch).
__global__ void prep2(int* __restrict__ bcursor, int nbuck,
                      const int* __restrict__ ei, int E, const int* __restrict__ misc,
                      const float* __restrict__ W1, const float* __restrict__ W2,
                      bf16* __restrict__ Wsw1, bf16* __restrict__ Wsw2,
                      int* __restrict__ cnt) {
    int bx = blockIdx.x;
    if (bx == 0) {
        for (int i = threadIdx.x; i < nbuck; i += 256) bcursor[i] = i * CAP;
    } else if (bx <= 16) {
        // frag f=kt*8+nt, lane l: n=l&15, k=(l>>4)*8+j
        int id = (bx - 1) * 256 + threadIdx.x;       // 0..4095
        const float* W = (id < 2048) ? W1 : W2;
        bf16* Wsw = (id < 2048) ? Wsw1 : Wsw2;
        int t = id & 2047;
        int f = t >> 6, l = t & 63;
        int kt = f >> 3, nt = f & 7;
        int q = l >> 4, m = l & 15;
        bf16 tmp[8];
        #pragma unroll
        for (int j = 0; j < 8; ++j)
            tmp[j] = __float2bfloat16(W[(size_t)(kt * 32 + q * 8 + j) * DIM + nt * 16 + m]);
        *(bf16x8*)(Wsw + (size_t)t * 8) = *(const bf16x8*)tmp;
    } else {
        int flagI = misc[1];
        int g0 = (bx - 17) * 256 + threadIdx.x;
        for (int e = g0; e < E; e += 64 * 256) {
            int d = (flagI == 0) ? ei[2 * E + 2 * e] : ei[E + e];
            atomicAdd(&cnt[d], 1);
        }
    }
}

// ===================== K2: dis = rsqrt(deg + 1) =============================
__global__ void dis_k(const int* __restrict__ cnt, float* __restrict__ dis, int N) {
    int i = blockIdx.x * 256 + threadIdx.x;
    if (i < N) dis[i] = rsqrtf((float)(cnt[i] + 1));
}

// ============================ MFMA gemm1 ====================================
// Y1'[node][c] = bf16( (X[node,:] @ W[:,c]) * dis[node] ) -- SINGLE rounding.
__device__ __forceinline__ void gemm_body(const float* __restrict__ Xv,
                                          const bf16* __restrict__ Wsw,
                                          const float* __restrict__ disv,
                                          bf16* __restrict__ Y, int N,
                                          int gw, int nw, int lane,
                                          float* sld) {
    int m = lane & 15, q = lane >> 4;
    const bf16x8* bp = (const bf16x8*)Wsw;          // frag f at bp[f*64 + lane]
    for (int t = gw; t * 16 + 16 <= N; t += nw) {
        int base = t * 16;
        bf16x8 a[4];
        const float* xp = Xv + (size_t)(base + m) * DIM + q * 8;
        #pragma unroll
        for (int kt = 0; kt < 4; ++kt) {
            float4 v0 = *(const float4*)(xp + kt * 32);
            float4 v1 = *(const float4*)(xp + kt * 32 + 4);
            bf16 tt[8] = {__float2bfloat16(v0.x), __float2bfloat16(v0.y),
                          __float2bfloat16(v0.z), __float2bfloat16(v0.w),
                          __float2bfloat16(v1.x), __float2bfloat16(v1.y),
                          __float2bfloat16(v1.z), __float2bfloat16(v1.w)};
            a[kt] = *(const bf16x8*)tt;
        }
        f32x4 acc[8];
        #pragma unroll
        for (int nt = 0; nt < 8; ++nt) acc[nt] = (f32x4){0.f, 0.f, 0.f, 0.f};
        #pragma unroll
        for (int kt = 0; kt < 4; ++kt) {
            #pragma unroll
            for (int nt = 0; nt < 8; ++nt) {
                bf16x8 bfr = bp[(size_t)(kt * 8 + nt) * 64 + lane];
                acc[nt] = __builtin_amdgcn_mfma_f32_16x16x32_bf16(a[kt], bfr, acc[nt], 0, 0, 0);
            }
        }
        // D: row (node) = q*4 + r, col (channel) = nt*16 + m
        #pragma unroll
        for (int nt = 0; nt < 8; ++nt)
            #pragma unroll
            for (int r = 0; r < 4; ++r)
                sld[(q * 4 + r) * 132 + nt * 16 + m] = acc[nt][r];
        asm volatile("s_waitcnt lgkmcnt(0)" ::: "memory");
        #pragma unroll
        for (int i = 0; i < 4; ++i) {
            int row = i * 4 + q;
            float ds = disv[base + row];
            const float* rp = sld + row * 132 + m * 8;
            float4 v0 = *(const float4*)rp;
            float4 v1 = *(const float4*)(rp + 4);
            alignas(16) bf16 tt[8] = {
                __float2bfloat16(v0.x * ds), __float2bfloat16(v0.y * ds),
                __float2bfloat16(v0.z * ds), __float2bfloat16(v0.w * ds),
                __float2bfloat16(v1.x * ds), __float2bfloat16(v1.y * ds),
                __float2bfloat16(v1.z * ds), __float2bfloat16(v1.w * ds)};
            *(uint4*)(Y + (size_t)(base + row) * DIM + m * 8) = *(const uint4*)tt;
        }
        asm volatile("s_waitcnt lgkmcnt(0)" ::: "memory");
    }
}

// ============================ K3: scatter || gemm1 ==========================
__global__ __launch_bounds__(256)
void scatter_gemm1(const int* __restrict__ ei, int E, const int* __restrict__ misc,
                   int* __restrict__ bcursor, unsigned* __restrict__ staged,
                   int nbuck, int nchunks,
                   const float* __restrict__ X, const bf16* __restrict__ Wsw,
                   const float* __restrict__ dis, bf16* __restrict__ Y, int N) {
    __shared__ float smem[4][16 * 132];             // 33.8 KB; scatter aliases it
    int bx = blockIdx.x;
    if (bx < nchunks) {
        int* s_cnt  = (int*)&smem[0][0];
        int* s_base = s_cnt + 512;
        int* s_fill = s_cnt + 1024;
        for (int i = threadIdx.x; i < nbuck; i += 256) { s_cnt[i] = 0; s_fill[i] = 0; }
        __syncthreads();
        int flagI = misc[1];
        int c0 = bx * CHUNK;
        int cn = min(E - c0, CHUNK);
        for (int i = threadIdx.x; i < cn; i += 256) {
            int e = c0 + i;
            int d = (flagI == 0) ? ei[2 * E + 2 * e] : ei[E + e];
            atomicAdd(&s_cnt[d >> 7], 1);
        }
        __syncthreads();
        for (int i = threadIdx.x; i < nbuck; i += 256) {
            int c = s_cnt[i];
            s_base[i] = c ? atomicAdd(&bcursor[i], c) : 0;
        }
        __syncthreads();
        for (int i = threadIdx.x; i < cn; i += 256) {
            int e = c0 + i;
            int s, d;
            if (flagI == 0) { s = ei[2 * e]; d = ei[2 * E + 2 * e]; }
            else            { s = ei[e];     d = ei[E + e]; }
            int b = d >> 7;
            int r = s_base[b] + atomicAdd(&s_fill[b], 1);
            if (r < (b + 1) * CAP)                           // overflow clamp (never hit)
                staged[r] = ((unsigned)s << 7) | (unsigned)(d & 127);
        }
    } else {
        int wid = threadIdx.x >> 6, lane = threadIdx.x & 63;
        int ngw = (gridDim.x - nchunks) * 4;
        gemm_body(X, Wsw, dis, Y, N, (bx - nchunks) * 4 + wid, ngw, lane, smem[wid]);
    }
}

// ============================ helpers =======================================
__device__ __forceinline__ void add8(float* a, uint4 v) {
    a[0] += __uint_as_float(v.x << 16);
    a[1] += __uint_as_float(v.x & 0xffff0000u);
    a[2] += __uint_as_float(v.y << 16);
    a[3] += __uint_as_float(v.y & 0xffff0000u);
    a[4] += __uint_as_float(v.z << 16);
    a[5] += __uint_as_float(v.z & 0xffff0000u);
    a[6] += __uint_as_float(v.w << 16);
    a[7] += __uint_as_float(v.w & 0xffff0000u);
}

// CSR gather-accumulate over a node's edges (inputs pre-scaled; pure adds).
__device__ __forceinline__ void row_accum(float acc[4][8], const uint4* __restrict__ Y,
                                          const int* __restrict__ csr,
                                          int e0, int e1, int cl) {
    int e = e0;
    while (e + 8 <= e1) {
        int s[8];
        #pragma unroll
        for (int j = 0; j < 8; ++j) s[j] = csr[e + j];
        uint4 v[8];
        #pragma unroll
        for (int j = 0; j < 8; ++j) v[j] = Y[(size_t)s[j] * 16 + cl];
        #pragma unroll
        for (int j = 0; j < 8; ++j) add8(acc[j & 3], v[j]);
        e += 8;
    }
    if (e + 4 <= e1) {
        int s[4];
        #pragma unroll
        for (int j = 0; j < 4; ++j) s[j] = csr[e + j];
        uint4 v[4];
        #pragma unroll
        for (int j = 0; j < 4; ++j) v[j] = Y[(size_t)s[j] * 16 + cl];
        #pragma unroll
        for (int j = 0; j < 4; ++j) add8(acc[j], v[j]);
        e += 4;
    }
    for (; e < e1; ++e)
        add8(acc[0], Y[(size_t)csr[e] * 16 + cl]);
}

// ============ K4: bucket sort + aggregate1 + gemm2 (fully fused) ============
// Phase S: counting-sort this bucket's slab -> csr slab, rowstart (global);
// Phase A: per-node CSR gather of pre-scaled Y1' rows (pure adds), finish
//          h = relu(dn*(sum + Y1'[n]) + b1) -> bf16 LDS tile;
// Phase B: 128x128 @ 128x128 MFMA (8 waves x 16 rows), epilogue staged in
//          LDS (aliased), store Y2' = bf16((h@W2)*dn) coalesced.
__global__ __launch_bounds__(512, 4)
void sort_agg1_gemm2(const uint4* __restrict__ Y, const unsigned* __restrict__ staged,
                     const int* __restrict__ bcursor, int* __restrict__ csr,
                     int* __restrict__ rowstart, const float* __restrict__ bias,
                     const bf16* __restrict__ Wsw, bf16* __restrict__ Y2, int N) {
    __shared__ int s_cnt[128], s_off[128], s_fill[128], s_scan[128];
    __shared__ __align__(16) float big[8 * 16 * 132];   // 67.6 KB; hT aliases it
    bf16* hT = (bf16*)big;                               // [128][136] bf16
    int tid = threadIdx.x;
    int b = blockIdx.x;
    int seg0 = b * CAP, base = b * 128;
    int n = min(bcursor[b] - seg0, CAP);

    // ---- Phase S: counting sort ----
    if (tid < 128) { s_cnt[tid] = 0; s_fill[tid] = 0; }
    __syncthreads();
    for (int i = tid; i < n; i += 512)
        atomicAdd(&s_cnt[staged[seg0 + i] & 127u], 1);
    __syncthreads();
    int v = (tid < 128) ? s_cnt[tid] : 0;
    if (tid < 128) s_scan[tid] = v;
    __syncthreads();
    for (int off = 1; off < 128; off <<= 1) {
        int t = (tid < 128 && tid >= off) ? s_scan[tid - off] : 0;
        __syncthreads();
        if (tid < 128) s_scan[tid] += t;
        __syncthreads();
    }
    if (tid < 128) {
        s_off[tid] = s_scan[tid] - v;
        int node = base + tid;
        if (node < N) rowstart[node] = seg0 + s_off[tid];   // cnt[] already = deg (K1)
    }
    __syncthreads();
    for (int i = tid; i < n; i += 512) {
        unsigned p = staged[seg0 + i];
        int dl = p & 127u;
        int r = atomicAdd(&s_fill[dl], 1);
        csr[seg0 + s_off[dl] + r] = (int)(p >> 7);
    }
    __threadfence_block();
    __syncthreads();

    // ---- Phase A: aggregate (pure adds; Y1' pre-scaled at gemm1) ----
    #pragma unroll
    for (int r4 = 0; r4 < 4; ++r4) {
        int lrow = r4 * 32 + (tid >> 4);        // 0..127
        int cl = tid & 15;
        int node = base + lrow;
        bool alive = node < N;
        float acc[4][8];
        #pragma unroll
        for (int j = 0; j < 4; ++j)
            #pragma unroll
            for (int k = 0; k < 8; ++k) acc[j][k] = 0.f;
        float dn = 0.f;
        if (alive) {
            dn = rsqrtf((float)(s_cnt[lrow] + 1));          // == dis[node] bit-exact
            add8(acc[3], Y[(size_t)node * 16 + cl]);        // self loop (pre-scaled)
            int e0 = seg0 + s_off[lrow];
            row_accum(acc, Y, csr, e0, e0 + s_cnt[lrow], cl);
        }
        float s8[8];
        #pragma unroll
        for (int k = 0; k < 8; ++k)
            s8[k] = (acc[0][k] + acc[1][k]) + (acc[2][k] + acc[3][k]);
        float4 b0 = ((const float4*)bias)[2 * cl];
        float4 b1 = ((const float4*)bias)[2 * cl + 1];
        float bb[8] = {b0.x, b0.y, b0.z, b0.w, b1.x, b1.y, b1.z, b1.w};
        alignas(16) bf16 hh[8];
        #pragma unroll
        for (int j = 0; j < 8; ++j)
            hh[j] = __float2bfloat16(alive ? fmaxf(dn * s8[j] + bb[j], 0.f) : 0.f);
        *(uint4*)&hT[(size_t)lrow * 136 + cl * 8] = *(const uint4*)hh;
    }
    __syncthreads();

    // ---- Phase B: MFMA; wave w -> rows w*16..w*16+15, all 128 cols ----
    int wave = tid >> 6, lane = tid & 63;
    int m = lane & 15, q = lane >> 4;
    bf16x8 a[4];
    #pragma unroll
    for (int kt = 0; kt < 4; ++kt)
        a[kt] = *(const bf16x8*)&hT[(size_t)(wave * 16 + m) * 136 + q * 8 + kt * 32];
    __syncthreads();                            // hT dead; s_out may overwrite

    const bf16x8* bp = (const bf16x8*)Wsw;
    f32x4 acc[8];
    #pragma unroll
    for (int nt = 0; nt < 8; ++nt) acc[nt] = (f32x4){0.f, 0.f, 0.f, 0.f};
    #pragma unroll
    for (int kt = 0; kt < 4; ++kt)
        #pragma unroll
        for (int nt = 0; nt < 8; ++nt) {
            bf16x8 bfr = bp[(size_t)(kt * 8 + nt) * 64 + lane];
            acc[nt] = __builtin_amdgcn_mfma_f32_16x16x32_bf16(a[kt], bfr, acc[nt], 0, 0, 0);
        }
    float* s_out = big + wave * (16 * 132);
    #pragma unroll
    for (int nt = 0; nt < 8; ++nt)
        #pragma unroll
        for (int r = 0; r < 4; ++r)
            s_out[(q * 4 + r) * 132 + nt * 16 + m] = acc[nt][r];
    asm volatile("s_waitcnt lgkmcnt(0)" ::: "memory");
    #pragma unroll
    for (int i = 0; i < 4; ++i) {
        int row = i * 4 + q;
        int lrow = wave * 16 + row;
        int node = base + lrow;
        if (node < N) {
            float ds = rsqrtf((float)(s_cnt[lrow] + 1));
            const float* rp = s_out + row * 132 + m * 8;
            float4 v0 = *(const float4*)rp;
            float4 v1 = *(const float4*)(rp + 4);
            alignas(16) bf16 tt[8] = {
                __float2bfloat16(v0.x * ds), __float2bfloat16(v0.y * ds),
                __float2bfloat16(v0.z * ds), __float2bfloat16(v0.w * ds),
                __float2bfloat16(v1.x * ds), __float2bfloat16(v1.y * ds),
                __float2bfloat16(v1.z * ds), __float2bfloat16(v1.w * ds)};
            *(uint4*)(Y2 + (size_t)node * DIM + m * 8) = *(const uint4*)tt;
        }
    }
}

// ================= K5: final aggregate (inputs pre-scaled) ==================
__global__ __launch_bounds__(256, 4)
void aggregate_final(const uint4* __restrict__ Y, const int* __restrict__ rowstart,
                     const int* __restrict__ cnt, const int* __restrict__ csr,
                     const float* __restrict__ dis, const float* __restrict__ bias,
                     float4* __restrict__ Of, int N) {
    int wave = threadIdx.x >> 6;
    int lane = threadIdx.x & 63;
    int sub = lane >> 4, cl = lane & 15;
    int node = blockIdx.x * 16 + wave * 4 + sub;
    if (node >= N) return;
    int e0 = rowstart[node], e1 = e0 + cnt[node];

    float acc[4][8];
    #pragma unroll
    for (int j = 0; j < 4; ++j)
        #pragma unroll
        for (int k = 0; k < 8; ++k) acc[j][k] = 0.f;

    float dn = dis[node];
    add8(acc[3], Y[(size_t)node * 16 + cl]);            // self loop (pre-scaled)
    row_accum(acc, Y, csr, e0, e1, cl);

    float s8[8];
    #pragma unroll
    for (int k = 0; k < 8; ++k)
        s8[k] = (acc[0][k] + acc[1][k]) + (acc[2][k] + acc[3][k]);

    float4 b0 = ((const float4*)bias)[2 * cl];
    float4 b1 = ((const float4*)bias)[2 * cl + 1];
    float o[8];
    o[0] = fmaxf(dn * s8[0] + b0.x, 0.f);
    o[1] = fmaxf(dn * s8[1] + b0.y, 0.f);
    o[2] = fmaxf(dn * s8[2] + b0.z, 0.f);
    o[3] = fmaxf(dn * s8[3] + b0.w, 0.f);
    o[4] = fmaxf(dn * s8[4] + b1.x, 0.f);
    o[5] = fmaxf(dn * s8[5] + b1.y, 0.f);
    o[6] = fmaxf(dn * s8[6] + b1.z, 0.f);
    o[7] = fmaxf(dn * s8[7] + b1.w, 0.f);
    Of[(size_t)node * 32 + 2 * cl]     = make_float4(o[0], o[1], o[2], o[3]);
    Of[(size_t)node * 32 + 2 * cl + 1] = make_float4(o[4], o[5], o[6], o[7]);
}

// ============================ launcher ======================================
extern "C" void kernel_launch(void* const* d_in, const int* in_sizes, int n_in,
                              void* d_out, int out_size, void* d_ws, size_t ws_size,
                              hipStream_t stream) {
    const float* x  = (const float*)d_in[0];
    const int*   ei = (const int*)d_in[1];
    const float* W1 = (const float*)d_in[2];
    const float* b1 = (const float*)d_in[3];
    const float* W2 = (const float*)d_in[4];
    const float* b2 = (const float*)d_in[5];

    int N = in_sizes[0] / DIM;      // 50000
    int E = in_sizes[1] / 2;        // 600000
    int nbuck = (N + 127) / 128;    // 391
    int nchunks = (E + CHUNK - 1) / CHUNK;  // 147

    char* w = (char*)d_ws;
    size_t used = 0;
    auto carve = [&](size_t bytes) {
        char* p = w + used;
        used += (bytes + 255) & ~(size_t)255;
        return p;
    };
    int*      misc     = (int*)     carve(256);              // [1]=flagI
    int*      bcursor  = (int*)     carve((size_t)(nbuck + 1) * 4);
    unsigned* staged   = (unsigned*)carve((size_t)nbuck * CAP * 4);   // 6.4 MB
    int*      csr      = (int*)     carve((size_t)nbuck * CAP * 4);   // 6.4 MB
    int*      rowstart = (int*)     carve((size_t)N * 4);
    int*      cnt      = (int*)     carve((size_t)N * 4);             // in-degree
    float*    dis      = (float*)   carve((size_t)N * 4);
    bf16*     ybuf     = (bf16*)    carve((size_t)N * DIM * 2);       // Y1' (pre-scaled)
    bf16*     hbuf     = (bf16*)    carve((size_t)N * DIM * 2);       // Y2' (pre-scaled)
    bf16*     Wsw1     = (bf16*)    carve((size_t)DIM * DIM * 2);
    bf16*     Wsw2     = (bf16*)    carve((size_t)DIM * DIM * 2);

    int zblocks = (N + 255) / 256;          // 196
    detect_zero<<<1 + zblocks, 256, 0, stream>>>(ei, E, misc, cnt, N);
    prep2<<<81, 256, 0, stream>>>(bcursor, nbuck, ei, E, misc, W1, W2, Wsw1, Wsw2, cnt);
    dis_k<<<zblocks, 256, 0, stream>>>(cnt, dis, N);
    scatter_gemm1<<<nchunks + 784, 256, 0, stream>>>(ei, E, misc, bcursor, staged,
                                                     nbuck, nchunks, x, Wsw1, dis, ybuf, N);
    sort_agg1_gemm2<<<nbuck, 512, 0, stream>>>((const uint4*)ybuf, staged, bcursor,
                                               csr, rowstart, b1, Wsw2, hbuf, N);
    int ablocks = (N + 15) / 16;            // 3125
    aggregate_final<<<ablocks, 256, 0, stream>>>((const uint4*)hbuf, rowstart, cnt, csr,
                                                 dis, b2, (float4*)d_out, N);
}

// Round 8
// 180.580 us; speedup vs baseline: 6.4935x; 1.1703x over previous
//
#include <hip/hip_runtime.h>
#include <hip/hip_bf16.h>

#define DIM 128
#define CHUNK 4096
#define CAP 4096        // slab capacity per 128-node bucket (65 sigma above mean)
typedef __hip_bfloat16 bf16;
typedef __attribute__((ext_vector_type(8))) short bf16x8;   // 8 bf16 = 4 VGPRs
typedef __attribute__((ext_vector_type(4))) float f32x4;

// ============================ K1: prep ======================================
__global__ void prep_kernel(int* __restrict__ bcursor, int nbuck,
                            const int* __restrict__ ei, int E, int* __restrict__ misc,
                            const float* __restrict__ W1, const float* __restrict__ W2,
                            bf16* __restrict__ Wsw1, bf16* __restrict__ Wsw2) {
    if (blockIdx.x == 0) {
        for (int i = threadIdx.x; i < nbuck; i += 256) bcursor[i] = i * CAP;
    } else if (blockIdx.x == 1) {
        __shared__ int s_or;
        if (threadIdx.x == 0) s_or = 0;
        __syncthreads();
        int lim = E < 16384 ? E : 16384;
        int acc = 0;
        for (int j = threadIdx.x; j < lim; j += 256) acc |= ei[2 * j + 1];
        if (acc) atomicOr(&s_or, 1);
        __syncthreads();
        if (threadIdx.x == 0) misc[1] = s_or;
    } else {
        // W f32 -> bf16 B-fragment order: frag f=kt*8+nt, lane l: n=l&15, k=(l>>4)*8+j
        int id = (blockIdx.x - 2) * 256 + threadIdx.x;       // 0..4095
        const float* W = (id < 2048) ? W1 : W2;
        bf16* Wsw = (id < 2048) ? Wsw1 : Wsw2;
        int t = id & 2047;
        int f = t >> 6, l = t & 63;
        int kt = f >> 3, nt = f & 7;
        int q = l >> 4, m = l & 15;
        bf16 tmp[8];
        #pragma unroll
        for (int j = 0; j < 8; ++j)
            tmp[j] = __float2bfloat16(W[(size_t)(kt * 32 + q * 8 + j) * DIM + nt * 16 + m]);
        *(bf16x8*)(Wsw + (size_t)t * 8) = *(const bf16x8*)tmp;
    }
}

// ============================ MFMA gemm1 ====================================
// Y[node][c] = bf16(X[node,:] @ W[:,c]); wave = 16 nodes x 128 cols.
// All 32 W fragments preloaded to registers (reused across ~4 tiles/wave).
// Epilogue: stage f32 acc through per-wave LDS tile [16][132], read back
// row-major, emit 4x dwordx4 coalesced stores.
__device__ __forceinline__ void gemm_body(const float* __restrict__ Xv,
                                          const bf16* __restrict__ Wsw,
                                          bf16* __restrict__ Y, int N,
                                          int gw, int nw, int lane,
                                          float* sld) {
    int m = lane & 15, q = lane >> 4;
    const bf16x8* bp = (const bf16x8*)Wsw;          // frag f at bp[f*64 + lane]
    bf16x8 wreg[32];
    #pragma unroll
    for (int f = 0; f < 32; ++f) wreg[f] = bp[(size_t)f * 64 + lane];
    for (int t = gw; t * 16 + 16 <= N; t += nw) {
        int base = t * 16;
        bf16x8 a[4];
        const float* xp = Xv + (size_t)(base + m) * DIM + q * 8;
        #pragma unroll
        for (int kt = 0; kt < 4; ++kt) {
            float4 v0 = *(const float4*)(xp + kt * 32);
            float4 v1 = *(const float4*)(xp + kt * 32 + 4);
            bf16 tt[8] = {__float2bfloat16(v0.x), __float2bfloat16(v0.y),
                          __float2bfloat16(v0.z), __float2bfloat16(v0.w),
                          __float2bfloat16(v1.x), __float2bfloat16(v1.y),
                          __float2bfloat16(v1.z), __float2bfloat16(v1.w)};
            a[kt] = *(const bf16x8*)tt;
        }
        f32x4 acc[8];
        #pragma unroll
        for (int nt = 0; nt < 8; ++nt) acc[nt] = (f32x4){0.f, 0.f, 0.f, 0.f};
        #pragma unroll
        for (int kt = 0; kt < 4; ++kt) {
            #pragma unroll
            for (int nt = 0; nt < 8; ++nt)
                acc[nt] = __builtin_amdgcn_mfma_f32_16x16x32_bf16(a[kt], wreg[kt * 8 + nt],
                                                                  acc[nt], 0, 0, 0);
        }
        // D: row (node) = q*4 + r, col (channel) = nt*16 + m
        #pragma unroll
        for (int nt = 0; nt < 8; ++nt)
            #pragma unroll
            for (int r = 0; r < 4; ++r)
                sld[(q * 4 + r) * 132 + nt * 16 + m] = acc[nt][r];
        asm volatile("s_waitcnt lgkmcnt(0)" ::: "memory");
        #pragma unroll
        for (int i = 0; i < 4; ++i) {
            int row = i * 4 + q;
            const float* rp = sld + row * 132 + m * 8;
            float4 v0 = *(const float4*)rp;
            float4 v1 = *(const float4*)(rp + 4);
            alignas(16) bf16 tt[8] = {
                __float2bfloat16(v0.x), __float2bfloat16(v0.y),
                __float2bfloat16(v0.z), __float2bfloat16(v0.w),
                __float2bfloat16(v1.x), __float2bfloat16(v1.y),
                __float2bfloat16(v1.z), __float2bfloat16(v1.w)};
            *(uint4*)(Y + (size_t)(base + row) * DIM + m * 8) = *(const uint4*)tt;
        }
        asm volatile("s_waitcnt lgkmcnt(0)" ::: "memory");
    }
}

// ============================ K2: scatter || gemm1 ==========================
__global__ __launch_bounds__(256)
void scatter_gemm1(const int* __restrict__ ei, int E, const int* __restrict__ misc,
                   int* __restrict__ bcursor, unsigned* __restrict__ staged,
                   int nbuck, int nchunks,
                   const float* __restrict__ X, const bf16* __restrict__ Wsw,
                   bf16* __restrict__ Y, int N) {
    __shared__ float smem[4][16 * 132];             // 33.8 KB; scatter aliases it
    int bx = blockIdx.x;
    if (bx < nchunks) {
        int* s_cnt  = (int*)&smem[0][0];
        int* s_base = s_cnt + 512;
        int* s_fill = s_cnt + 1024;
        for (int i = threadIdx.x; i < nbuck; i += 256) { s_cnt[i] = 0; s_fill[i] = 0; }
        __syncthreads();
        int flagI = misc[1];
        int c0 = bx * CHUNK;
        int cn = min(E - c0, CHUNK);
        for (int i = threadIdx.x; i < cn; i += 256) {
            int e = c0 + i;
            int d = (flagI == 0) ? ei[2 * E + 2 * e] : ei[E + e];
            atomicAdd(&s_cnt[d >> 7], 1);
        }
        __syncthreads();
        for (int i = threadIdx.x; i < nbuck; i += 256) {
            int c = s_cnt[i];
            s_base[i] = c ? atomicAdd(&bcursor[i], c) : 0;
        }
        __syncthreads();
        for (int i = threadIdx.x; i < cn; i += 256) {
            int e = c0 + i;
            int s, d;
            if (flagI == 0) { s = ei[2 * e]; d = ei[2 * E + 2 * e]; }
            else            { s = ei[e];     d = ei[E + e]; }
            int b = d >> 7;
            int r = s_base[b] + atomicAdd(&s_fill[b], 1);
            if (r < (b + 1) * CAP)                           // overflow clamp (never hit)
                staged[r] = ((unsigned)s << 7) | (unsigned)(d & 127);
        }
    } else {
        int wid = threadIdx.x >> 6, lane = threadIdx.x & 63;
        int ngw = (gridDim.x - nchunks) * 4;
        gemm_body(X, Wsw, Y, N, (bx - nchunks) * 4 + wid, ngw, lane, smem[wid]);
    }
}

// ================ K3: within-bucket sort + dis ==============================
__global__ void bucket_sort(const unsigned* __restrict__ staged,
                            const int* __restrict__ bcursor,
                            int* __restrict__ csr, int* __restrict__ rowstart,
                            int* __restrict__ cnt, float* __restrict__ dis, int N) {
    __shared__ int s_cnt[128], s_off[128], s_fill[128], s_scan[128];
    int b = blockIdx.x, tid = threadIdx.x;
    int seg0 = b * CAP;
    int n = min(bcursor[b] - seg0, CAP);
    if (tid < 128) { s_cnt[tid] = 0; s_fill[tid] = 0; }
    __syncthreads();
    for (int i = tid; i < n; i += 256)
        atomicAdd(&s_cnt[staged[seg0 + i] & 127u], 1);
    __syncthreads();
    int v = (tid < 128) ? s_cnt[tid] : 0;
    if (tid < 128) s_scan[tid] = v;
    __syncthreads();
    for (int off = 1; off < 128; off <<= 1) {
        int t = (tid < 128 && tid >= off) ? s_scan[tid - off] : 0;
        __syncthreads();
        if (tid < 128) s_scan[tid] += t;
        __syncthreads();
    }
    if (tid < 128) {
        s_off[tid] = s_scan[tid] - v;
        int node = b * 128 + tid;
        if (node < N) {
            cnt[node] = v;
            rowstart[node] = seg0 + s_off[tid];
            dis[node] = rsqrtf((float)(v + 1));   // +1 self loop
        }
    }
    __syncthreads();
    for (int i = tid; i < n; i += 256) {
        unsigned p = staged[seg0 + i];
        int dl = p & 127u;
        int r = atomicAdd(&s_fill[dl], 1);
        csr[seg0 + s_off[dl] + r] = (int)(p >> 7);
    }
}

// ============================ helpers =======================================
__device__ __forceinline__ void fma8(float* a, uint4 v, float ds) {
    a[0] = fmaf(__uint_as_float(v.x << 16), ds, a[0]);
    a[1] = fmaf(__uint_as_float(v.x & 0xffff0000u), ds, a[1]);
    a[2] = fmaf(__uint_as_float(v.y << 16), ds, a[2]);
    a[3] = fmaf(__uint_as_float(v.y & 0xffff0000u), ds, a[3]);
    a[4] = fmaf(__uint_as_float(v.z << 16), ds, a[4]);
    a[5] = fmaf(__uint_as_float(v.z & 0xffff0000u), ds, a[5]);
    a[6] = fmaf(__uint_as_float(v.w << 16), ds, a[6]);
    a[7] = fmaf(__uint_as_float(v.w & 0xffff0000u), ds, a[7]);
}

__device__ __forceinline__ void add8(float* a, uint4 v) {
    a[0] += __uint_as_float(v.x << 16);
    a[1] += __uint_as_float(v.x & 0xffff0000u);
    a[2] += __uint_as_float(v.y << 16);
    a[3] += __uint_as_float(v.y & 0xffff0000u);
    a[4] += __uint_as_float(v.z << 16);
    a[5] += __uint_as_float(v.z & 0xffff0000u);
    a[6] += __uint_as_float(v.w << 16);
    a[7] += __uint_as_float(v.w & 0xffff0000u);
}

// ================= K4: aggregate1 + gemm2 (fused, pre-scaled out) ===========
// Phase A: h[n] = relu(dn*(Y1[n]*dn + sum Y1[s]*ds) + b1)  -> LDS (never global)
// Phase B: per-block 16x128 @ 128x128 MFMA on LDS h-tile
// Phase C: Y2'[n][c] = bf16( (h@W2)[n][c] * dis[n] )  -> coalesced store
__global__ __launch_bounds__(256, 4)
void agg1_gemm2(const uint4* __restrict__ Y, const int* __restrict__ rowstart,
                const int* __restrict__ cnt, const int* __restrict__ csr,
                const float* __restrict__ dis, const float* __restrict__ bias,
                const bf16* __restrict__ Wsw, bf16* __restrict__ Y2, int N) {
    __shared__ __align__(16) bf16 h_lds[16][136];   // row stride 272B = 17x16B
    __shared__ float s_out[16 * 132];
    int wave = threadIdx.x >> 6, lane = threadIdx.x & 63;
    int sub = lane >> 4, cl = lane & 15;
    int base = blockIdx.x * 16;
    int node = base + wave * 4 + sub;
    bool alive = node < N;

    // ---- Phase A ----
    float acc[4][8];
    #pragma unroll
    for (int j = 0; j < 4; ++j)
        #pragma unroll
        for (int k = 0; k < 8; ++k) acc[j][k] = 0.f;

    float dn = 0.f;
    if (alive) {
        int e0 = rowstart[node], e1 = e0 + cnt[node];
        dn = dis[node];
        fma8(acc[3], Y[(size_t)node * 16 + cl], dn);        // self loop

        int e = e0;
        while (e + 8 <= e1) {
            int s[8];
            #pragma unroll
            for (int j = 0; j < 8; ++j) s[j] = csr[e + j];
            uint4 v[8]; float dv[8];
            #pragma unroll
            for (int j = 0; j < 8; ++j) { v[j] = Y[(size_t)s[j] * 16 + cl]; dv[j] = dis[s[j]]; }
            #pragma unroll
            for (int j = 0; j < 8; ++j) fma8(acc[j & 3], v[j], dv[j]);
            e += 8;
        }
        if (e + 4 <= e1) {
            int s[4];
            #pragma unroll
            for (int j = 0; j < 4; ++j) s[j] = csr[e + j];
            uint4 v[4]; float dv[4];
            #pragma unroll
            for (int j = 0; j < 4; ++j) { v[j] = Y[(size_t)s[j] * 16 + cl]; dv[j] = dis[s[j]]; }
            #pragma unroll
            for (int j = 0; j < 4; ++j) fma8(acc[j], v[j], dv[j]);
            e += 4;
        }
        for (; e < e1; ++e) {
            int s = csr[e];
            fma8(acc[0], Y[(size_t)s * 16 + cl], dis[s]);
        }
    }
    {
        float s8[8];
        #pragma unroll
        for (int k = 0; k < 8; ++k)
            s8[k] = (acc[0][k] + acc[1][k]) + (acc[2][k] + acc[3][k]);
        float4 b0 = ((const float4*)bias)[2 * cl];
        float4 b1 = ((const float4*)bias)[2 * cl + 1];
        alignas(16) bf16 t[8];
        t[0] = __float2bfloat16(alive ? fmaxf(dn * s8[0] + b0.x, 0.f) : 0.f);
        t[1] = __float2bfloat16(alive ? fmaxf(dn * s8[1] + b0.y, 0.f) : 0.f);
        t[2] = __float2bfloat16(alive ? fmaxf(dn * s8[2] + b0.z, 0.f) : 0.f);
        t[3] = __float2bfloat16(alive ? fmaxf(dn * s8[3] + b0.w, 0.f) : 0.f);
        t[4] = __float2bfloat16(alive ? fmaxf(dn * s8[4] + b1.x, 0.f) : 0.f);
        t[5] = __float2bfloat16(alive ? fmaxf(dn * s8[5] + b1.y, 0.f) : 0.f);
        t[6] = __float2bfloat16(alive ? fmaxf(dn * s8[6] + b1.z, 0.f) : 0.f);
        t[7] = __float2bfloat16(alive ? fmaxf(dn * s8[7] + b1.w, 0.f) : 0.f);
        *(uint4*)&h_lds[wave * 4 + sub][cl * 8] = *(const uint4*)t;
    }
    __syncthreads();

    // ---- Phase B: 16x128 @ 128x128 MFMA; wave handles nt = {wave*2, wave*2+1} ----
    int m = cl, q = sub;
    bf16x8 a[4];
    #pragma unroll
    for (int kt = 0; kt < 4; ++kt)
        a[kt] = *(const bf16x8*)&h_lds[m][q * 8 + kt * 32];
    const bf16x8* bp = (const bf16x8*)Wsw;
    f32x4 g[2];
    g[0] = (f32x4){0.f, 0.f, 0.f, 0.f};
    g[1] = (f32x4){0.f, 0.f, 0.f, 0.f};
    #pragma unroll
    for (int kt = 0; kt < 4; ++kt) {
        #pragma unroll
        for (int j = 0; j < 2; ++j) {
            int nt = wave * 2 + j;
            bf16x8 bfr = bp[(size_t)(kt * 8 + nt) * 64 + lane];
            g[j] = __builtin_amdgcn_mfma_f32_16x16x32_bf16(a[kt], bfr, g[j], 0, 0, 0);
        }
    }
    #pragma unroll
    for (int j = 0; j < 2; ++j)
        #pragma unroll
        for (int r = 0; r < 4; ++r)
            s_out[(q * 4 + r) * 132 + (wave * 2 + j) * 16 + m] = g[j][r];
    __syncthreads();

    // ---- Phase C: coalesced, dis-pre-scaled bf16 store ----
    int on = threadIdx.x >> 4;
    int oc = (threadIdx.x & 15) * 8;
    if (base + on < N) {
        float ds = dis[base + on];
        const float* rp = s_out + on * 132 + oc;
        float4 v0 = *(const float4*)rp;
        float4 v1 = *(const float4*)(rp + 4);
        alignas(16) bf16 t[8] = {
            __float2bfloat16(v0.x * ds), __float2bfloat16(v0.y * ds),
            __float2bfloat16(v0.z * ds), __float2bfloat16(v0.w * ds),
            __float2bfloat16(v1.x * ds), __float2bfloat16(v1.y * ds),
            __float2bfloat16(v1.z * ds), __float2bfloat16(v1.w * ds)};
        *(uint4*)(Y2 + (size_t)(base + on) * DIM + oc) = *(const uint4*)t;
    }
}

// ================= K5: final aggregate (inputs pre-scaled) ==================
// 12-deep gather batches: more rows in flight per quarter-wave while staying
// under 128 VGPR (so launch_bounds(256,4) does not spill).
__global__ __launch_bounds__(256, 4)
void aggregate_final(const uint4* __restrict__ Y, const int* __restrict__ rowstart,
                     const int* __restrict__ cnt, const int* __restrict__ csr,
                     const float* __restrict__ dis, const float* __restrict__ bias,
                     float* __restrict__ Of, int N) {
    int wave = threadIdx.x >> 6;
    int lane = threadIdx.x & 63;
    int sub = lane >> 4, cl = lane & 15;
    int node = blockIdx.x * 16 + wave * 4 + sub;
    if (node >= N) return;
    int e0 = rowstart[node], e1 = e0 + cnt[node];

    float acc[4][8];
    #pragma unroll
    for (int j = 0; j < 4; ++j)
        #pragma unroll
        for (int k = 0; k < 8; ++k) acc[j][k] = 0.f;

    float dn = dis[node];
    add8(acc[3], Y[(size_t)node * 16 + cl]);            // self loop (pre-scaled)

    int e = e0;
    while (e + 12 <= e1) {
        int s[12];
        #pragma unroll
        for (int j = 0; j < 12; ++j) s[j] = csr[e + j];
        uint4 v[12];
        #pragma unroll
        for (int j = 0; j < 12; ++j) v[j] = Y[(size_t)s[j] * 16 + cl];
        #pragma unroll
        for (int j = 0; j < 12; ++j) add8(acc[j & 3], v[j]);
        e += 12;
    }
    if (e + 8 <= e1) {
        int s[8];
        #pragma unroll
        for (int j = 0; j < 8; ++j) s[j] = csr[e + j];
        uint4 v[8];
        #pragma unroll
        for (int j = 0; j < 8; ++j) v[j] = Y[(size_t)s[j] * 16 + cl];
        #pragma unroll
        for (int j = 0; j < 8; ++j) add8(acc[j & 3], v[j]);
        e += 8;
    }
    if (e + 4 <= e1) {
        int s[4];
        #pragma unroll
        for (int j = 0; j < 4; ++j) s[j] = csr[e + j];
        uint4 v[4];
        #pragma unroll
        for (int j = 0; j < 4; ++j) v[j] = Y[(size_t)s[j] * 16 + cl];
        #pragma unroll
        for (int j = 0; j < 4; ++j) add8(acc[j], v[j]);
        e += 4;
    }
    for (; e < e1; ++e)
        add8(acc[0], Y[(size_t)csr[e] * 16 + cl]);

    float s8[8];
    #pragma unroll
    for (int k = 0; k < 8; ++k)
        s8[k] = (acc[0][k] + acc[1][k]) + (acc[2][k] + acc[3][k]);

    float4 b0 = ((const float4*)bias)[2 * cl];
    float4 b1 = ((const float4*)bias)[2 * cl + 1];
    f32x4 o0, o1;
    o0[0] = fmaxf(dn * s8[0] + b0.x, 0.f);
    o0[1] = fmaxf(dn * s8[1] + b0.y, 0.f);
    o0[2] = fmaxf(dn * s8[2] + b0.z, 0.f);
    o0[3] = fmaxf(dn * s8[3] + b0.w, 0.f);
    o1[0] = fmaxf(dn * s8[4] + b1.x, 0.f);
    o1[1] = fmaxf(dn * s8[5] + b1.y, 0.f);
    o1[2] = fmaxf(dn * s8[6] + b1.z, 0.f);
    o1[3] = fmaxf(dn * s8[7] + b1.w, 0.f);
    // Output is never re-read: nontemporal keeps L2 clean for the Y2' gathers.
    f32x4* op = (f32x4*)(Of + (size_t)node * DIM + cl * 8);
    __builtin_nontemporal_store(o0, op);
    __builtin_nontemporal_store(o1, op + 1);
}

// ============================ launcher ======================================
extern "C" void kernel_launch(void* const* d_in, const int* in_sizes, int n_in,
                              void* d_out, int out_size, void* d_ws, size_t ws_size,
                              hipStream_t stream) {
    const float* x  = (const float*)d_in[0];
    const int*   ei = (const int*)d_in[1];
    const float* W1 = (const float*)d_in[2];
    const float* b1 = (const float*)d_in[3];
    const float* W2 = (const float*)d_in[4];
    const float* b2 = (const float*)d_in[5];

    int N = in_sizes[0] / DIM;      // 50000
    int E = in_sizes[1] / 2;        // 600000
    int nbuck = (N + 127) / 128;    // 391
    int nchunks = (E + CHUNK - 1) / CHUNK;  // 147

    char* w = (char*)d_ws;
    size_t used = 0;
    auto carve = [&](size_t bytes) {
        char* p = w + used;
        used += (bytes + 255) & ~(size_t)255;
        return p;
    };
    int*      misc     = (int*)     carve(256);              // [1]=flagI
    int*      bcursor  = (int*)     carve((size_t)(nbuck + 1) * 4);
    unsigned* staged   = (unsigned*)carve((size_t)nbuck * CAP * 4);   // 6.4 MB
    int*      csr      = (int*)     carve((size_t)nbuck * CAP * 4);   // 6.4 MB
    int*      rowstart = (int*)     carve((size_t)N * 4);
    int*      cnt      = (int*)     carve((size_t)N * 4);
    float*    dis      = (float*)   carve((size_t)N * 4);
    bf16*     ybuf     = (bf16*)    carve((size_t)N * DIM * 2);       // Y1
    bf16*     hbuf     = (bf16*)    carve((size_t)N * DIM * 2);       // Y2' (pre-scaled)
    bf16*     Wsw1     = (bf16*)    carve((size_t)DIM * DIM * 2);
    bf16*     Wsw2     = (bf16*)    carve((size_t)DIM * DIM * 2);

    prep_kernel <<<18, 256, 0, stream>>>(bcursor, nbuck, ei, E, misc, W1, W2, Wsw1, Wsw2);
    // 196 gemm blocks -> ~4 tiles/wave so the register-preloaded W is reused.
    scatter_gemm1<<<nchunks + 196, 256, 0, stream>>>(ei, E, misc, bcursor, staged,
                                                     nbuck, nchunks, x, Wsw1, ybuf, N);
    bucket_sort <<<nbuck, 256, 0, stream>>>(staged, bcursor, csr, rowstart, cnt, dis, N);

    int ablocks = (N + 15) / 16;            // 3125
    agg1_gemm2<<<ablocks, 256, 0, stream>>>((const uint4*)ybuf, rowstart, cnt, csr,
                                            dis, b1, Wsw2, hbuf, N);
    aggregate_final<<<ablocks, 256, 0, stream>>>((const uint4*)hbuf, rowstart, cnt, csr,
                                                 dis, b2, (float*)d_out, N);
}